// Round 6
// baseline (3040.838 us; speedup 1.0000x reference)
//
#include <hip/hip_runtime.h>
#include <math.h>

// Problem constants
constexpr int cS  = 16;
constexpr int cB  = 8;
constexpr int cNC = 5;
constexpr int cD  = 256;
constexpr int cP  = 16;
constexpr int cPD = 49;
constexpr int cDFT = 128;
constexpr int cEP  = 64;
#define LEPS 1e-5f

__device__ __forceinline__ float gelu_t(float x) {
  float x3 = x * x * x;
  return 0.5f * x * (1.0f + tanhf(0.7978845608028654f * (x + 0.044715f * x3)));
}
__device__ __forceinline__ float sigm(float x) { return 1.0f / (1.0f + __expf(-x)); }

struct Params {
  const float* x; const int* fb; const float* inW; const float* inb;
  const float *tkWy, *tkWq, *tkWk, *tkwb, *tklng, *tklnb;
  const float *tkmg, *tkmb, *tkmW1, *tkmb1, *tkmW2, *tkmb2;
  const float *chWy, *chWq, *chWk, *chwb, *chlng, *chlnb;
  const float *chmg, *chmb, *chmW1, *chmb1, *chmW2, *chmb2;
  const float *flng, *flnb;
  const float *oWy, *oWq, *oWk, *owb, *olng, *olnb, *outW, *outb;
  float* h; float* gbuf; float* outp;
};

// LDS overlays (re-carved per stage; stages separated by __syncthreads)
struct TM { float W1s[1024]; float W2s[1024]; float pt1[2][4][4][16]; float pt2[2][4][4][16]; };
struct CSm { float pS[2][4][4]; float pQ[2][4][4]; };
struct CM { float xv[32][256]; float hid[32][128]; };
struct FL { float sacc[2][4][4][256]; };
struct OS { float pS[2][4]; float pQ[2][4]; float pr[2][4][cNC]; };

// R5: ONE plain kernel, 8 blocks (one per batch element) x 1024 threads.
// The whole model is independent per b (token SRWM couples p within (b,d);
// channel SRWM couples d within (b,p); mixers are per-(s,b) rows) -> all
// inter-stage ordering is __syncthreads(), no grid sync, no cooperative API
// (which silently failed to launch in R4). 16 waves/CU gives 4 waves/SIMD
// of latency hiding during the scans (vs 1 in the multi-kernel version).
__global__ __launch_bounds__(1024) void k_all(Params p) {
  const int b = blockIdx.x;
  const int t = threadIdx.x;
  __shared__ __align__(16) char smraw[53376];
  float* h = p.h;

  // ====================== embed: patchify + onehot + linear ===============
  {
    float* Win = (float*)smraw;                 // [49][256] = 50176 B
    float* img = (float*)(smraw + 50176);       // [784]
    for (int idx = t; idx < cPD * cD; idx += 1024) Win[idx] = p.inW[idx];
    const int d  = t & 255;
    const int pg = t >> 8;
    __syncthreads();
    for (int s = 0; s < cS; ++s) {
      for (int idx = t; idx < 784; idx += 1024)
        img[idx] = p.x[(size_t)(s * cB + b) * 784 + idx];
      __syncthreads();
      const int cls = p.fb[s * cB + b];
      const float base0 = p.inb[d] + p.inW[(size_t)(cPD + cls) * cD + d];
#pragma unroll
      for (int pi = 0; pi < 4; ++pi) {
        const int pp = pg * 4 + pi;
        const int ph = pp >> 2, pw = pp & 3;
        float acc = base0;
#pragma unroll
        for (int j = 0; j < cPD; ++j)
          acc += img[(ph * 7 + j / 7) * 28 + pw * 7 + (j % 7)] * Win[j * cD + d];
        h[((size_t)(s * cB + b) * cP + pp) * cD + d] = acc;
      }
      __syncthreads();
    }
  }

  for (int i = 0; i < 2; ++i) {
    // =================== token SRWM (64 groups x 4 passes) ===============
    {
      const float* Wy0 = p.tkWy + i * 256;
      const float* Wq0 = p.tkWq + i * 256;
      const float* Wk0 = p.tkWk + i * 256;
      const float* wb0 = p.tkwb + i * 64;
      const int g16 = t >> 4;
      const int r   = t & 15;
      const float gg = p.tklng[i * 16 + r], bb = p.tklnb[i * 16 + r];
      for (int pass = 0; pass < 4; ++pass) {
        const int d = g16 + (pass << 6);
        float wy[16], wq[16], wk[16], wbr[16];
#pragma unroll
        for (int j = 0; j < 16; ++j) {
          wy[j]  = Wy0[r * 16 + j];
          wq[j]  = Wq0[r * 16 + j];
          wk[j]  = Wk0[r * 16 + j];
          wbr[j] = wb0[(r & 3) * 16 + j];
        }
        float xp[16];
#pragma unroll
        for (int s = 0; s < 16; ++s)
          xp[s] = h[((size_t)(s * cB + b) * cP + r) * cD + d];
        for (int s = 0; s < cS; ++s) {
          const float xv = xp[s];
          float y = 0.f, q = 0.f, k = 0.f, bt = 0.f;
#pragma unroll
          for (int j = 0; j < 16; ++j) {
            const float xj = __shfl(xv, j, 16);
            y += wy[j] * xj; q += wq[j] * xj; k += wk[j] * xj; bt += wbr[j] * xj;
          }
          const float bsig = sigm(bt);
          const float b0  = __shfl(bsig, 0, 16);
          const float b1v = __shfl(bsig, 1, 16);
          const float b2v = __shfl(bsig, 2, 16);
          const float b3v = __shfl(bsig, 3, 16);
          const float eq = __expf(q), ek = __expf(k);
          float sq = eq, sk = ek;
#pragma unroll
          for (int o = 1; o < 16; o <<= 1) {
            sq += __shfl_xor(sq, o, 16);
            sk += __shfl_xor(sk, o, 16);
          }
          const float qs = eq / sq, ks = ek / sk;
          float ay = 0.f, vyk = 0.f, vqq = 0.f, vqk = 0.f, vkq = 0.f, vkk = 0.f, vbq = 0.f, vbk = 0.f;
#pragma unroll
          for (int j = 0; j < 16; ++j) {
            const float qj = __shfl(qs, j, 16);
            const float kj = __shfl(ks, j, 16);
            ay  += wy[j]  * qj; vyk += wy[j]  * kj;
            vqq += wq[j]  * qj; vqk += wq[j]  * kj;
            vkq += wk[j]  * qj; vkk += wk[j]  * kj;
            vbq += wbr[j] * qj; vbk += wbr[j] * kj;
          }
          const float ea = __expf(ay);
          float sa = ea;
#pragma unroll
          for (int o = 1; o < 16; o <<= 1) sa += __shfl_xor(sa, o, 16);
          const float vyq = ea / sa;
          const float cy = b0 * (vyq - vyk), cq = b1v * (vqq - vqk);
          const float ck = b2v * (vkq - vkk), cb = b3v * (vbq - vbk);
#pragma unroll
          for (int j = 0; j < 16; ++j) {
            const float kj = __shfl(ks, j, 16);
            wy[j] += cy * kj; wq[j] += cq * kj; wk[j] += ck * kj; wbr[j] += cb * kj;
          }
          float s1 = y, s2 = y * y;
#pragma unroll
          for (int o = 1; o < 16; o <<= 1) {
            s1 += __shfl_xor(s1, o, 16);
            s2 += __shfl_xor(s2, o, 16);
          }
          const float m = s1 * 0.0625f;
          const float var = s2 * 0.0625f - m * m;
          h[((size_t)(s * cB + b) * cP + r) * cD + d] =
              (y - m) * rsqrtf(var + LEPS) * gg + bb;
        }
      }
      __syncthreads();
    }

    // =================== token mixer (4 s-rows per round) ================
    {
      TM* sm = (TM*)smraw;
      const float* W1 = p.tkmW1 + i * 1024;
      const float* W2 = p.tkmW2 + i * 1024;
      const float* b1 = p.tkmb1 + i * 64;
      const float* b2 = p.tkmb2 + i * 16;
      const int sub = t >> 8, tt = t & 255;
      const int lane = t & 63, w4 = (t >> 6) & 3;
      const float gd = p.tkmg[i * 256 + tt], bd = p.tkmb[i * 256 + tt];
      sm->W1s[t] = W1[t];
      sm->W2s[t] = W2[t];
      __syncthreads();
      for (int round = 0; round < 4; ++round) {
        const int s = round * 4 + sub;
        const size_t base = ((size_t)(s * cB + b) * cP) * cD + tt;
        float xr[16];
#pragma unroll
        for (int pp = 0; pp < 16; ++pp) xr[pp] = h[base + pp * cD];
        float keep1 = 0.f, keep2 = 0.f;
        const int mypp = t & 15;
#pragma unroll
        for (int pp = 0; pp < 16; ++pp) {
          float a = xr[pp], c = xr[pp] * xr[pp];
#pragma unroll
          for (int o = 1; o < 64; o <<= 1) {
            a += __shfl_xor(a, o, 64);
            c += __shfl_xor(c, o, 64);
          }
          if (mypp == pp) { keep1 = a; keep2 = c; }
        }
        const int db = round & 1;
        if (lane < 16) {
          sm->pt1[db][sub][w4][lane] = keep1;
          sm->pt2[db][sub][w4][lane] = keep2;
        }
        __syncthreads();
        float v[16], out[16];
#pragma unroll
        for (int pp = 0; pp < 16; ++pp) {
          const float s1 = sm->pt1[db][sub][0][pp] + sm->pt1[db][sub][1][pp] +
                           sm->pt1[db][sub][2][pp] + sm->pt1[db][sub][3][pp];
          const float s2 = sm->pt2[db][sub][0][pp] + sm->pt2[db][sub][1][pp] +
                           sm->pt2[db][sub][2][pp] + sm->pt2[db][sub][3][pp];
          const float m = s1 * (1.f / 256.f);
          const float rst = rsqrtf(s2 * (1.f / 256.f) - m * m + LEPS);
          v[pp] = (xr[pp] - m) * rst * gd + bd;
          out[pp] = b2[pp];
        }
        for (int e = 0; e < cEP; ++e) {
          float acc = b1[e];
#pragma unroll
          for (int pp = 0; pp < 16; ++pp) acc += v[pp] * sm->W1s[pp * 64 + e];
          const float ge = gelu_t(acc);
#pragma unroll
          for (int pp = 0; pp < 16; ++pp) out[pp] += ge * sm->W2s[e * 16 + pp];
        }
#pragma unroll
        for (int pp = 0; pp < 16; ++pp) h[base + pp * cD] = xr[pp] + out[pp];
      }
      __syncthreads();
    }

    // =================== channel SRWM (4 instances per round) ============
    {
      CSm* sm = (CSm*)smraw;
      const float* Wy0 = p.chWy + i * 4096;
      const float* Wq0 = p.chWq + i * 4096;
      const float* Wk0 = p.chWk + i * 4096;
      const float* wb0 = p.chwb + i * 1024;
      const int c  = t >> 8;
      const int tt = t & 255;
      const int hh = tt >> 4, r = tt & 15;
      const int w4 = tt >> 6;
      const float gg = p.chlng[i * 256 + tt], bb = p.chlnb[i * 256 + tt];
      for (int round = 0; round < 4; ++round) {
        const int pidx = round * 4 + c;
        const int bp = b * cP + pidx;
        float wy[16], wq[16], wk[16], wbr[16];
#pragma unroll
        for (int j = 0; j < 16; ++j) {
          wy[j]  = Wy0[(hh * 16 + r) * 16 + j];
          wq[j]  = Wq0[(hh * 16 + r) * 16 + j];
          wk[j]  = Wk0[(hh * 16 + r) * 16 + j];
          wbr[j] = wb0[(hh * 4 + (r & 3)) * 16 + j];
        }
        float xp[16];
#pragma unroll
        for (int s = 0; s < 16; ++s)
          xp[s] = h[(size_t)(s * cB * cP + bp) * cD + tt];
        for (int s = 0; s < cS; ++s) {
          const float xv = xp[s];
          float y = 0.f, q = 0.f, k = 0.f, bt = 0.f;
#pragma unroll
          for (int j = 0; j < 16; ++j) {
            const float xj = __shfl(xv, j, 16);
            y += wy[j] * xj; q += wq[j] * xj; k += wk[j] * xj; bt += wbr[j] * xj;
          }
          const float bsig = sigm(bt);
          const float b0  = __shfl(bsig, 0, 16);
          const float b1v = __shfl(bsig, 1, 16);
          const float b2v = __shfl(bsig, 2, 16);
          const float b3v = __shfl(bsig, 3, 16);
          const float eq = __expf(q), ek = __expf(k);
          float sq = eq, sk = ek;
#pragma unroll
          for (int o = 1; o < 16; o <<= 1) {
            sq += __shfl_xor(sq, o, 16);
            sk += __shfl_xor(sk, o, 16);
          }
          const float qs = eq / sq, ks = ek / sk;
          float ay = 0.f, vyk = 0.f, vqq = 0.f, vqk = 0.f, vkq = 0.f, vkk = 0.f, vbq = 0.f, vbk = 0.f;
#pragma unroll
          for (int j = 0; j < 16; ++j) {
            const float qj = __shfl(qs, j, 16);
            const float kj = __shfl(ks, j, 16);
            ay  += wy[j]  * qj; vyk += wy[j]  * kj;
            vqq += wq[j]  * qj; vqk += wq[j]  * kj;
            vkq += wk[j]  * qj; vkk += wk[j]  * kj;
            vbq += wbr[j] * qj; vbk += wbr[j] * kj;
          }
          const float ea = __expf(ay);
          float sa = ea;
#pragma unroll
          for (int o = 1; o < 16; o <<= 1) sa += __shfl_xor(sa, o, 16);
          const float vyq = ea / sa;
          const float cy = b0 * (vyq - vyk), cq = b1v * (vqq - vqk);
          const float ck = b2v * (vkq - vkk), cb = b3v * (vbq - vbk);
#pragma unroll
          for (int j = 0; j < 16; ++j) {
            const float kj = __shfl(ks, j, 16);
            wy[j] += cy * kj; wq[j] += cq * kj; wk[j] += ck * kj; wbr[j] += cb * kj;
          }
          float s1 = y, s2 = y * y;
#pragma unroll
          for (int o = 1; o < 64; o <<= 1) {
            s1 += __shfl_xor(s1, o, 64);
            s2 += __shfl_xor(s2, o, 64);
          }
          const int db = s & 1;
          if ((t & 63) == 0) { sm->pS[db][c][w4] = s1; sm->pQ[db][c][w4] = s2; }
          __syncthreads();
          const float sm1 = sm->pS[db][c][0] + sm->pS[db][c][1] + sm->pS[db][c][2] + sm->pS[db][c][3];
          const float sm2 = sm->pQ[db][c][0] + sm->pQ[db][c][1] + sm->pQ[db][c][2] + sm->pQ[db][c][3];
          const float m = sm1 * (1.f / 256.f);
          const float var = sm2 * (1.f / 256.f) - m * m;
          h[(size_t)(s * cB * cP + bp) * cD + tt] =
              (y - m) * rsqrtf(var + LEPS) * gg + bb;
        }
      }
      __syncthreads();
    }

    // =================== channel mixer (32 rows per round) ===============
    {
      CM* sm = (CM*)smraw;
      const float* W1 = p.chmW1 + i * 32768;
      const float* b1 = p.chmb1 + i * 128;
      const float* W2 = p.chmW2 + i * 32768;
      const float* b2 = p.chmb2 + i * 256;
      const int r32 = t >> 5, l = t & 31;
      const float4 g0 = ((const float4*)(p.chmg + i * 256))[l * 2];
      const float4 g1 = ((const float4*)(p.chmg + i * 256))[l * 2 + 1];
      const float4 q0 = ((const float4*)(p.chmb + i * 256))[l * 2];
      const float4 q1 = ((const float4*)(p.chmb + i * 256))[l * 2 + 1];
      for (int round = 0; round < 8; ++round) {
        const int rl = round * 32 + r32;
        const int s = rl >> 4, pp = rl & 15;
        const size_t grow = ((size_t)(s * cB + b) * cP + pp) * cD;
        const float4 x0 = ((const float4*)(h + grow))[l * 2];
        const float4 x1 = ((const float4*)(h + grow))[l * 2 + 1];
        float s1 = x0.x + x0.y + x0.z + x0.w + x1.x + x1.y + x1.z + x1.w;
        float s2 = x0.x * x0.x + x0.y * x0.y + x0.z * x0.z + x0.w * x0.w +
                   x1.x * x1.x + x1.y * x1.y + x1.z * x1.z + x1.w * x1.w;
#pragma unroll
        for (int o = 1; o < 32; o <<= 1) {
          s1 += __shfl_xor(s1, o, 32);
          s2 += __shfl_xor(s2, o, 32);
        }
        const float m = s1 * (1.f / 256.f);
        const float rst = rsqrtf(s2 * (1.f / 256.f) - m * m + LEPS);
        float4 L0, L1;
        L0.x = (x0.x - m) * rst * g0.x + q0.x; L0.y = (x0.y - m) * rst * g0.y + q0.y;
        L0.z = (x0.z - m) * rst * g0.z + q0.z; L0.w = (x0.w - m) * rst * g0.w + q0.w;
        L1.x = (x1.x - m) * rst * g1.x + q1.x; L1.y = (x1.y - m) * rst * g1.y + q1.y;
        L1.z = (x1.z - m) * rst * g1.z + q1.z; L1.w = (x1.w - m) * rst * g1.w + q1.w;
        ((float4*)sm->xv[r32])[l * 2]     = L0;
        ((float4*)sm->xv[r32])[l * 2 + 1] = L1;
        __syncthreads();
        {
          const float4* W1f = (const float4*)W1;
          float4 acc = ((const float4*)b1)[l];
          for (int j = 0; j < 256; ++j) {
            const float xj = sm->xv[r32][j];
            const float4 wv = W1f[j * 32 + l];
            acc.x += xj * wv.x; acc.y += xj * wv.y; acc.z += xj * wv.z; acc.w += xj * wv.w;
          }
          float4 hv;
          hv.x = gelu_t(acc.x); hv.y = gelu_t(acc.y);
          hv.z = gelu_t(acc.z); hv.w = gelu_t(acc.w);
          ((float4*)sm->hid[r32])[l] = hv;
        }
        __syncthreads();
        {
          const float4* W2f = (const float4*)W2;
          float4 a0 = ((const float4*)b2)[l * 2];
          float4 a1 = ((const float4*)b2)[l * 2 + 1];
          for (int e = 0; e < 128; ++e) {
            const float xh = sm->hid[r32][e];
            const float4 w0 = W2f[e * 64 + l * 2];
            const float4 w1 = W2f[e * 64 + l * 2 + 1];
            a0.x += xh * w0.x; a0.y += xh * w0.y; a0.z += xh * w0.z; a0.w += xh * w0.w;
            a1.x += xh * w1.x; a1.y += xh * w1.y; a1.z += xh * w1.z; a1.w += xh * w1.w;
          }
          a0.x += x0.x; a0.y += x0.y; a0.z += x0.z; a0.w += x0.w;
          a1.x += x1.x; a1.y += x1.y; a1.z += x1.z; a1.w += x1.w;
          ((float4*)(h + grow))[l * 2]     = a0;
          ((float4*)(h + grow))[l * 2 + 1] = a1;
        }
        __syncthreads();
      }
    }
  }

  // ====================== final LN + mean over patches ====================
  {
    FL* sm = (FL*)smraw;
    const int sub = t >> 8, tt = t & 255;
    const int lane = t & 63, w4 = (t >> 6) & 3;
    const float4 g4 = ((const float4*)p.flng)[lane];
    const float4 b4 = ((const float4*)p.flnb)[lane];
    for (int round = 0; round < 4; ++round) {
      const int s = round * 4 + sub;
      float a0 = 0.f, a1 = 0.f, a2 = 0.f, a3 = 0.f;
#pragma unroll
      for (int pi = 0; pi < 4; ++pi) {
        const int pp = w4 * 4 + pi;
        const float4 v4 = ((const float4*)(h + ((size_t)(s * cB + b) * cP + pp) * cD))[lane];
        float s1 = v4.x + v4.y + v4.z + v4.w;
        float s2 = v4.x * v4.x + v4.y * v4.y + v4.z * v4.z + v4.w * v4.w;
#pragma unroll
        for (int o = 1; o < 64; o <<= 1) {
          s1 += __shfl_xor(s1, o, 64);
          s2 += __shfl_xor(s2, o, 64);
        }
        const float m = s1 * (1.f / 256.f);
        const float rst = rsqrtf(s2 * (1.f / 256.f) - m * m + LEPS);
        a0 += (v4.x - m) * rst * g4.x + b4.x;
        a1 += (v4.y - m) * rst * g4.y + b4.y;
        a2 += (v4.z - m) * rst * g4.z + b4.z;
        a3 += (v4.w - m) * rst * g4.w + b4.w;
      }
      const int db = round & 1;
      ((float4*)sm->sacc[db][sub][w4])[lane] = make_float4(a0, a1, a2, a3);
      __syncthreads();
      p.gbuf[(size_t)(s * cB + b) * cD + tt] =
          (sm->sacc[db][sub][0][tt] + sm->sacc[db][sub][1][tt] +
           sm->sacc[db][sub][2][tt] + sm->sacc[db][sub][3][tt]) * (1.f / 16.f);
    }
    __syncthreads();
  }

  // ====================== output SRWM + projection ========================
  // Waves 4..15 run redundant identical copies (same inputs -> same values);
  // only waves 0..3 write LDS partials; all threads hit the barriers.
  {
    OS* sm = (OS*)smraw;
    const int tt = t & 255;
    const int hh = tt >> 4, r = tt & 15;
    const int w4 = (tt >> 6);
    float wy[16], wq[16], wk[16], wbr[16];
#pragma unroll
    for (int j = 0; j < 16; ++j) {
      wy[j]  = p.oWy[(hh * 16 + r) * 16 + j];
      wq[j]  = p.oWq[(hh * 16 + r) * 16 + j];
      wk[j]  = p.oWk[(hh * 16 + r) * 16 + j];
      wbr[j] = p.owb[(hh * 4 + (r & 3)) * 16 + j];
    }
    float wrow[cNC];
#pragma unroll
    for (int c = 0; c < cNC; ++c) wrow[c] = p.outW[(size_t)tt * cNC + c];
    const float gg = p.olng[tt], bb = p.olnb[tt];
    float xp[16];
#pragma unroll
    for (int s = 0; s < 16; ++s)
      xp[s] = p.gbuf[(size_t)(s * cB + b) * cD + tt];
    for (int s = 0; s < cS; ++s) {
      const float xv = xp[s];
      float y = 0.f, q = 0.f, k = 0.f, bt = 0.f;
#pragma unroll
      for (int j = 0; j < 16; ++j) {
        const float xj = __shfl(xv, j, 16);
        y += wy[j] * xj; q += wq[j] * xj; k += wk[j] * xj; bt += wbr[j] * xj;
      }
      const float bsig = sigm(bt);
      const float b0  = __shfl(bsig, 0, 16);
      const float b1v = __shfl(bsig, 1, 16);
      const float b2v = __shfl(bsig, 2, 16);
      const float b3v = __shfl(bsig, 3, 16);
      const float eq = __expf(q), ek = __expf(k);
      float sq = eq, sk = ek;
#pragma unroll
      for (int o = 1; o < 16; o <<= 1) {
        sq += __shfl_xor(sq, o, 16);
        sk += __shfl_xor(sk, o, 16);
      }
      const float qs = eq / sq, ks = ek / sk;
      float ay = 0.f, vyk = 0.f, vqq = 0.f, vqk = 0.f, vkq = 0.f, vkk = 0.f, vbq = 0.f, vbk = 0.f;
#pragma unroll
      for (int j = 0; j < 16; ++j) {
        const float qj = __shfl(qs, j, 16);
        const float kj = __shfl(ks, j, 16);
        ay  += wy[j]  * qj; vyk += wy[j]  * kj;
        vqq += wq[j]  * qj; vqk += wq[j]  * kj;
        vkq += wk[j]  * qj; vkk += wk[j]  * kj;
        vbq += wbr[j] * qj; vbk += wbr[j] * kj;
      }
      const float ea = __expf(ay);
      float sa = ea;
#pragma unroll
      for (int o = 1; o < 16; o <<= 1) sa += __shfl_xor(sa, o, 16);
      const float vyq = ea / sa;
      const float cy = b0 * (vyq - vyk), cq = b1v * (vqq - vqk);
      const float ck = b2v * (vkq - vkk), cb = b3v * (vbq - vbk);
#pragma unroll
      for (int j = 0; j < 16; ++j) {
        const float kj = __shfl(ks, j, 16);
        wy[j] += cy * kj; wq[j] += cq * kj; wk[j] += ck * kj; wbr[j] += cb * kj;
      }
      float s1 = y, s2 = y * y;
#pragma unroll
      for (int o = 1; o < 64; o <<= 1) {
        s1 += __shfl_xor(s1, o, 64);
        s2 += __shfl_xor(s2, o, 64);
      }
      const int db = s & 1;
      if (t < 256 && (t & 63) == 0) { sm->pS[db][w4] = s1; sm->pQ[db][w4] = s2; }
      __syncthreads();
      const float sm1 = sm->pS[db][0] + sm->pS[db][1] + sm->pS[db][2] + sm->pS[db][3];
      const float sm2 = sm->pQ[db][0] + sm->pQ[db][1] + sm->pQ[db][2] + sm->pQ[db][3];
      const float m = sm1 * (1.f / 256.f);
      const float var = sm2 * (1.f / 256.f) - m * m;
      const float lnt = (y - m) * rsqrtf(var + LEPS) * gg + bb;
      float pv[cNC];
#pragma unroll
      for (int c = 0; c < cNC; ++c) {
        float pvv = lnt * wrow[c];
#pragma unroll
        for (int o = 1; o < 64; o <<= 1) pvv += __shfl_xor(pvv, o, 64);
        pv[c] = pvv;
      }
      if (t < 256 && (t & 63) == 0) {
#pragma unroll
        for (int c = 0; c < cNC; ++c) sm->pr[db][w4][c] = pv[c];
      }
      __syncthreads();
      if (t < cNC) {
        p.outp[(size_t)(s * cB + b) * cNC + t] =
            p.outb[t] + sm->pr[db][0][t] + sm->pr[db][1][t] +
            sm->pr[db][2][t] + sm->pr[db][3][t];
      }
    }
  }
}

extern "C" void kernel_launch(void* const* d_in, const int* in_sizes, int n_in,
                              void* d_out, int out_size, void* d_ws, size_t ws_size,
                              hipStream_t stream) {
  Params prm;
  prm.x     = (const float*)d_in[0];
  prm.fb    = (const int*)d_in[1];
  prm.inW   = (const float*)d_in[2];
  prm.inb   = (const float*)d_in[3];
  prm.tkWy  = (const float*)d_in[4];
  prm.tkWq  = (const float*)d_in[5];
  prm.tkWk  = (const float*)d_in[6];
  prm.tkwb  = (const float*)d_in[7];
  prm.tklng = (const float*)d_in[8];
  prm.tklnb = (const float*)d_in[9];
  prm.tkmg  = (const float*)d_in[10];
  prm.tkmb  = (const float*)d_in[11];
  prm.tkmW1 = (const float*)d_in[12];
  prm.tkmb1 = (const float*)d_in[13];
  prm.tkmW2 = (const float*)d_in[14];
  prm.tkmb2 = (const float*)d_in[15];
  prm.chWy  = (const float*)d_in[16];
  prm.chWq  = (const float*)d_in[17];
  prm.chWk  = (const float*)d_in[18];
  prm.chwb  = (const float*)d_in[19];
  prm.chlng = (const float*)d_in[20];
  prm.chlnb = (const float*)d_in[21];
  prm.chmg  = (const float*)d_in[22];
  prm.chmb  = (const float*)d_in[23];
  prm.chmW1 = (const float*)d_in[24];
  prm.chmb1 = (const float*)d_in[25];
  prm.chmW2 = (const float*)d_in[26];
  prm.chmb2 = (const float*)d_in[27];
  prm.flng  = (const float*)d_in[28];
  prm.flnb  = (const float*)d_in[29];
  prm.oWy   = (const float*)d_in[30];
  prm.oWq   = (const float*)d_in[31];
  prm.oWk   = (const float*)d_in[32];
  prm.owb   = (const float*)d_in[33];
  prm.olng  = (const float*)d_in[34];
  prm.olnb  = (const float*)d_in[35];
  prm.outW  = (const float*)d_in[36];
  prm.outb  = (const float*)d_in[37];
  prm.h     = (float*)d_ws;
  prm.gbuf  = prm.h + (size_t)cS * cB * cP * cD;
  prm.outp  = (float*)d_out;

  k_all<<<dim3(cB), dim3(1024), 0, stream>>>(prm);
}

// Round 7
// 366.825 us; speedup vs baseline: 8.2896x; 8.2896x over previous
//
#include <hip/hip_runtime.h>
#include <math.h>

// Problem constants (from reference)
constexpr int cS  = 16;   // sequence
constexpr int cB  = 8;    // batch
constexpr int cNC = 5;    // classes
constexpr int cD  = 256;  // hidden
constexpr int cP  = 16;   // patches
constexpr int cPD = 49;   // patch dim
constexpr int cDFT = 128; // channel-mixer hidden
constexpr int cEP  = 64;  // token-mixer hidden (EF*P)
#define LEPS 1e-5f

__device__ __forceinline__ float gelu_t(float x) {
  float x3 = x * x * x;
  return 0.5f * x * (1.0f + tanhf(0.7978845608028654f * (x + 0.044715f * x3)));
}
__device__ __forceinline__ float sigm(float x) { return 1.0f / (1.0f + __expf(-x)); }

// ---- DPP 16-lane reductions: 4 dependent VALU ops (~25cyc) instead of 4
// ---- ds_swizzle shuffles (~160cyc). quad_perm xor1/xor2 then row_ror 4/8;
// ---- any fixed rotation set covering all 4 quads yields the full row sum.
template<int CTRL>
__device__ __forceinline__ float dpp_mov(float v) {
  return __int_as_float(__builtin_amdgcn_update_dpp(
      0, __float_as_int(v), CTRL, 0xF, 0xF, true));
}
__device__ __forceinline__ float row_sum16(float v) {
  v += dpp_mov<0xB1>(v);   // quad_perm [1,0,3,2]  (xor 1)
  v += dpp_mov<0x4E>(v);   // quad_perm [2,3,0,1]  (xor 2)
  v += dpp_mov<0x124>(v);  // row_ror:4
  v += dpp_mov<0x128>(v);  // row_ror:8
  return v;
}
__device__ __forceinline__ float wave_sum64(float v) {
  v = row_sum16(v);
  v += __shfl_xor(v, 16, 64);
  v += __shfl_xor(v, 32, 64);
  return v;
}
__device__ __forceinline__ float frcp(float x) { return __builtin_amdgcn_rcpf(x); }

// ---------------- embed: patchify + one-hot concat + linear ----------------
__global__ __launch_bounds__(256) void k_embed(const float* __restrict__ x,
                                               const int* __restrict__ fb,
                                               const float* __restrict__ inW,
                                               const float* __restrict__ inb,
                                               float* __restrict__ h) {
  const int blk = blockIdx.x;
  const int p  = blk & 15;
  const int sb = blk >> 4;
  const int ph = p >> 2, pw = p & 3;
  __shared__ float sx[cPD];
  const int t = threadIdx.x;
  if (t < cPD) {
    const int p1 = t / 7, p2 = t % 7;
    sx[t] = x[(size_t)sb * 784 + (ph * 7 + p1) * 28 + (pw * 7 + p2)];
  }
  __syncthreads();
  const int cls = fb[sb];
  float acc = inb[t] + inW[(size_t)(cPD + cls) * cD + t];
#pragma unroll
  for (int j = 0; j < cPD; ++j) acc += sx[j] * inW[(size_t)j * cD + t];
  h[((size_t)sb * cP + p) * cD + t] = acc;
}

// ---------------- token SRWM: wave-centric, DPP + deferred-normalize -------
// grid = 128 blocks x 256 threads; instance = (b, d); feature axis = patch r.
__global__ __launch_bounds__(256) void k_tok_srwm(
    float* __restrict__ h, const float* __restrict__ Wy0, const float* __restrict__ Wq0,
    const float* __restrict__ Wk0, const float* __restrict__ wb0,
    const float* __restrict__ lng, const float* __restrict__ lnb) {
  const int t    = threadIdx.x;
  const int lane = t & 63;
  const int w    = t >> 6;
  const int r    = lane & 15;
  const int li   = lane >> 4;
  const int b    = blockIdx.x >> 4;
  const int d    = ((blockIdx.x & 15) << 4) + (w << 2) + li;
  float wy[16], wq[16], wk[16], wbr[16];
#pragma unroll
  for (int j = 0; j < 16; ++j) {
    wy[j]  = Wy0[r * 16 + j];
    wq[j]  = Wq0[r * 16 + j];
    wk[j]  = Wk0[r * 16 + j];
    wbr[j] = wb0[(r & 3) * 16 + j];
  }
  const float gg = lng[r], bb = lnb[r];
  float xp[16];
#pragma unroll
  for (int s = 0; s < 16; ++s)
    xp[s] = h[((size_t)(s * cB + b) * cP + r) * cD + d];
  for (int s = 0; s < cS; ++s) {
    const float xv = xp[s];
    float y = 0.f, q = 0.f, k = 0.f, bt = 0.f;
#pragma unroll
    for (int j = 0; j < 16; ++j) {
      const float xj = __shfl(xv, j, 16);
      y += wy[j] * xj; q += wq[j] * xj; k += wk[j] * xj; bt += wbr[j] * xj;
    }
    const float bsig = sigm(bt);
    const float eq = __expf(q), ek = __expf(k);
    // un-normalized dots; sum-reduction overlaps them
    float ay = 0.f, vyk = 0.f, vqq = 0.f, vqk = 0.f, vkq = 0.f, vkk = 0.f, vbq = 0.f, vbk = 0.f;
    float ksj[16];
#pragma unroll
    for (int j = 0; j < 16; ++j) {
      const float qj = __shfl(eq, j, 16);
      const float kj = __shfl(ek, j, 16);
      ksj[j] = kj;
      ay  += wy[j]  * qj; vyk += wy[j]  * kj;
      vqq += wq[j]  * qj; vqk += wq[j]  * kj;
      vkq += wk[j]  * qj; vkk += wk[j]  * kj;
      vbq += wbr[j] * qj; vbk += wbr[j] * kj;
    }
    const float rq = frcp(row_sum16(eq));
    const float rk = frcp(row_sum16(ek));
    const float ea = __expf(ay * rq);
    const float vyq = ea * frcp(row_sum16(ea));
    const float b0  = __shfl(bsig, 0, 16);
    const float b1v = __shfl(bsig, 1, 16);
    const float b2v = __shfl(bsig, 2, 16);
    const float b3v = __shfl(bsig, 3, 16);
    // fold ks normalization (rk) into the coefficients
    const float cy = b0  * (vyq      - vyk * rk) * rk;
    const float cq = b1v * (vqq * rq - vqk * rk) * rk;
    const float ck = b2v * (vkq * rq - vkk * rk) * rk;
    const float cb = b3v * (vbq * rq - vbk * rk) * rk;
#pragma unroll
    for (int j = 0; j < 16; ++j) {
      wy[j] += cy * ksj[j]; wq[j] += cq * ksj[j]; wk[j] += ck * ksj[j]; wbr[j] += cb * ksj[j];
    }
    const float s1 = row_sum16(y);
    const float s2 = row_sum16(y * y);
    const float m = s1 * 0.0625f;
    const float var = s2 * 0.0625f - m * m;
    h[((size_t)(s * cB + b) * cP + r) * cD + d] = (y - m) * rsqrtf(var + LEPS) * gg + bb;
  }
}

// ---------------- token mixer: LN(D) then FFN over patch axis --------------
__global__ __launch_bounds__(256) void k_tok_mixer(
    float* __restrict__ h, const float* __restrict__ g, const float* __restrict__ bta,
    const float* __restrict__ W1, const float* __restrict__ b1,
    const float* __restrict__ W2, const float* __restrict__ b2) {
  const int sb = blockIdx.x;
  const int t = threadIdx.x;
  __shared__ float tile[16][256];
  __shared__ float W1s[16 * 64], W2s[64 * 16];
  __shared__ float mean_[16], rstd_[16];
  __shared__ float red[16][17], red2[16][17];
  const size_t base = (size_t)sb * cP * cD;
#pragma unroll
  for (int p = 0; p < 16; ++p) tile[p][t] = h[base + p * 256 + t];
  W1s[t] = W1[t]; W1s[t + 256] = W1[t + 256]; W1s[t + 512] = W1[t + 512]; W1s[t + 768] = W1[t + 768];
  W2s[t] = W2[t]; W2s[t + 256] = W2[t + 256]; W2s[t + 512] = W2[t + 512]; W2s[t + 768] = W2[t + 768];
  __syncthreads();
  const int p = t >> 4, l = t & 15;
  float ps = 0.f, ps2 = 0.f;
#pragma unroll
  for (int k = 0; k < 16; ++k) { const float v = tile[p][l + 16 * k]; ps += v; ps2 += v * v; }
  red[p][l] = ps; red2[p][l] = ps2;
  __syncthreads();
  if (t < 16) {
    float sm = 0.f, s2 = 0.f;
#pragma unroll
    for (int k = 0; k < 16; ++k) { sm += red[t][k]; s2 += red2[t][k]; }
    const float m = sm * (1.f / 256.f);
    mean_[t] = m;
    rstd_[t] = rsqrtf(s2 * (1.f / 256.f) - m * m + LEPS);
  }
  __syncthreads();
  const float gd = g[t], bd = bta[t];
  float v[16], out[16];
#pragma unroll
  for (int pp = 0; pp < 16; ++pp) {
    v[pp] = (tile[pp][t] - mean_[pp]) * rstd_[pp] * gd + bd;
    out[pp] = b2[pp];
  }
  for (int e = 0; e < cEP; ++e) {
    float acc = b1[e];
#pragma unroll
    for (int pp = 0; pp < 16; ++pp) acc += v[pp] * W1s[pp * 64 + e];
    const float ge = gelu_t(acc);
#pragma unroll
    for (int pp = 0; pp < 16; ++pp) out[pp] += ge * W2s[e * 16 + pp];
  }
#pragma unroll
  for (int pp = 0; pp < 16; ++pp) h[base + pp * 256 + t] = tile[pp][t] + out[pp];
}

// ---------------- channel SRWM + FUSED channel mixer -----------------------
// grid = B*P = 128 blocks x 256 threads. Scan output lives only in LDS
// (yout); the mixer (which is the sole consumer) runs as an epilogue and
// writes the final residual h to global. Saves 2 kernels + 4MB traffic.
__global__ __launch_bounds__(256, 1) void k_ch_srwm_mix(
    float* __restrict__ h, const float* __restrict__ Wy0, const float* __restrict__ Wq0,
    const float* __restrict__ Wk0, const float* __restrict__ wb0,
    const float* __restrict__ lng, const float* __restrict__ lnb,
    const float* __restrict__ mg, const float* __restrict__ mb,
    const float* __restrict__ W1, const float* __restrict__ b1,
    const float* __restrict__ W2, const float* __restrict__ b2) {
  const int t = threadIdx.x;
  const int w = t >> 6;
  const int hh = t >> 4, r = t & 15;
  const int bp = blockIdx.x;
  __shared__ float yout[16][256];
  __shared__ float lnv[8][256];
  __shared__ float hid[8][128];
  __shared__ float pS[2][4], pQ[2][4];
  {
    float wy[16], wq[16], wk[16], wbr[16];
#pragma unroll
    for (int j = 0; j < 16; ++j) {
      wy[j]  = Wy0[(hh * 16 + r) * 16 + j];
      wq[j]  = Wq0[(hh * 16 + r) * 16 + j];
      wk[j]  = Wk0[(hh * 16 + r) * 16 + j];
      wbr[j] = wb0[(hh * 4 + (r & 3)) * 16 + j];
    }
    const float gg = lng[t], bb = lnb[t];
    float xp[16];
#pragma unroll
    for (int s = 0; s < 16; ++s)
      xp[s] = h[(size_t)(s * cB * cP + bp) * cD + t];
    for (int s = 0; s < cS; ++s) {
      const float xv = xp[s];
      float y = 0.f, q = 0.f, k = 0.f, bt = 0.f;
#pragma unroll
      for (int j = 0; j < 16; ++j) {
        const float xj = __shfl(xv, j, 16);
        y += wy[j] * xj; q += wq[j] * xj; k += wk[j] * xj; bt += wbr[j] * xj;
      }
      const float bsig = sigm(bt);
      const float eq = __expf(q), ek = __expf(k);
      float ay = 0.f, vyk = 0.f, vqq = 0.f, vqk = 0.f, vkq = 0.f, vkk = 0.f, vbq = 0.f, vbk = 0.f;
      float ksj[16];
#pragma unroll
      for (int j = 0; j < 16; ++j) {
        const float qj = __shfl(eq, j, 16);
        const float kj = __shfl(ek, j, 16);
        ksj[j] = kj;
        ay  += wy[j]  * qj; vyk += wy[j]  * kj;
        vqq += wq[j]  * qj; vqk += wq[j]  * kj;
        vkq += wk[j]  * qj; vkk += wk[j]  * kj;
        vbq += wbr[j] * qj; vbk += wbr[j] * kj;
      }
      const float rq = frcp(row_sum16(eq));
      const float rk = frcp(row_sum16(ek));
      const float ea = __expf(ay * rq);
      const float vyq = ea * frcp(row_sum16(ea));
      const float b0  = __shfl(bsig, 0, 16);
      const float b1v = __shfl(bsig, 1, 16);
      const float b2v = __shfl(bsig, 2, 16);
      const float b3v = __shfl(bsig, 3, 16);
      const float cy = b0  * (vyq      - vyk * rk) * rk;
      const float cq = b1v * (vqq * rq - vqk * rk) * rk;
      const float ck = b2v * (vkq * rq - vkk * rk) * rk;
      const float cb = b3v * (vbq * rq - vbk * rk) * rk;
#pragma unroll
      for (int j = 0; j < 16; ++j) {
        wy[j] += cy * ksj[j]; wq[j] += cq * ksj[j]; wk[j] += ck * ksj[j]; wbr[j] += cb * ksj[j];
      }
      float s1 = row_sum16(y);
      float s2 = row_sum16(y * y);
      s1 += __shfl_xor(s1, 16, 64); s1 += __shfl_xor(s1, 32, 64);
      s2 += __shfl_xor(s2, 16, 64); s2 += __shfl_xor(s2, 32, 64);
      const int db = s & 1;
      if ((t & 63) == 0) { pS[db][w] = s1; pQ[db][w] = s2; }
      __syncthreads();
      const float sm1 = pS[db][0] + pS[db][1] + pS[db][2] + pS[db][3];
      const float sm2 = pQ[db][0] + pQ[db][1] + pQ[db][2] + pQ[db][3];
      const float m = sm1 * (1.f / 256.f);
      const float var = sm2 * (1.f / 256.f) - m * m;
      yout[s][t] = (y - m) * rsqrtf(var + LEPS) * gg + bb;
    }
  }
  __syncthreads();
  // ---- fused channel mixer over the 16 rows (s) this block owns ----
  {
    const int r32 = t >> 5, l = t & 31;
    const float4 g0 = ((const float4*)mg)[l * 2];
    const float4 g1 = ((const float4*)mg)[l * 2 + 1];
    const float4 q0 = ((const float4*)mb)[l * 2];
    const float4 q1 = ((const float4*)mb)[l * 2 + 1];
    for (int grp = 0; grp < 2; ++grp) {
      const int s = grp * 8 + r32;
      const float4 x0 = ((const float4*)yout[s])[l * 2];
      const float4 x1 = ((const float4*)yout[s])[l * 2 + 1];
      float s1 = x0.x + x0.y + x0.z + x0.w + x1.x + x1.y + x1.z + x1.w;
      float s2 = x0.x * x0.x + x0.y * x0.y + x0.z * x0.z + x0.w * x0.w +
                 x1.x * x1.x + x1.y * x1.y + x1.z * x1.z + x1.w * x1.w;
#pragma unroll
      for (int o = 1; o < 32; o <<= 1) {
        s1 += __shfl_xor(s1, o, 32);
        s2 += __shfl_xor(s2, o, 32);
      }
      const float m = s1 * (1.f / 256.f);
      const float rst = rsqrtf(s2 * (1.f / 256.f) - m * m + LEPS);
      float4 L0, L1;
      L0.x = (x0.x - m) * rst * g0.x + q0.x; L0.y = (x0.y - m) * rst * g0.y + q0.y;
      L0.z = (x0.z - m) * rst * g0.z + q0.z; L0.w = (x0.w - m) * rst * g0.w + q0.w;
      L1.x = (x1.x - m) * rst * g1.x + q1.x; L1.y = (x1.y - m) * rst * g1.y + q1.y;
      L1.z = (x1.z - m) * rst * g1.z + q1.z; L1.w = (x1.w - m) * rst * g1.w + q1.w;
      ((float4*)lnv[r32])[l * 2]     = L0;
      ((float4*)lnv[r32])[l * 2 + 1] = L1;
      __syncthreads();
      {
        const float4* W1f = (const float4*)W1;
        float4 acc = ((const float4*)b1)[l];
        for (int j = 0; j < 256; ++j) {
          const float xj = lnv[r32][j];
          const float4 wv = W1f[j * 32 + l];
          acc.x += xj * wv.x; acc.y += xj * wv.y; acc.z += xj * wv.z; acc.w += xj * wv.w;
        }
        float4 hv;
        hv.x = gelu_t(acc.x); hv.y = gelu_t(acc.y);
        hv.z = gelu_t(acc.z); hv.w = gelu_t(acc.w);
        ((float4*)hid[r32])[l] = hv;
      }
      __syncthreads();
      {
        const float4* W2f = (const float4*)W2;
        float4 a0 = ((const float4*)b2)[l * 2];
        float4 a1 = ((const float4*)b2)[l * 2 + 1];
        for (int e = 0; e < 128; ++e) {
          const float xh = hid[r32][e];
          const float4 w0 = W2f[e * 64 + l * 2];
          const float4 w1 = W2f[e * 64 + l * 2 + 1];
          a0.x += xh * w0.x; a0.y += xh * w0.y; a0.z += xh * w0.z; a0.w += xh * w0.w;
          a1.x += xh * w1.x; a1.y += xh * w1.y; a1.z += xh * w1.z; a1.w += xh * w1.w;
        }
        a0.x += x0.x; a0.y += x0.y; a0.z += x0.z; a0.w += x0.w;
        a1.x += x1.x; a1.y += x1.y; a1.z += x1.z; a1.w += x1.w;
        float4* op = (float4*)(h + (size_t)(s * cB * cP + bp) * cD);
        op[l * 2]     = a0;
        op[l * 2 + 1] = a1;
      }
      __syncthreads();
    }
  }
}

// ---------------- final LN + mean over patches -----------------------------
__global__ __launch_bounds__(256) void k_fln_mean(
    const float* __restrict__ h, const float* __restrict__ gg, const float* __restrict__ bbv,
    float* __restrict__ o) {
  const int sb = blockIdx.x;
  const int t = threadIdx.x;
  const int lane = t & 63, w = t >> 6;
  const float4 g4 = ((const float4*)gg)[lane];
  const float4 b4 = ((const float4*)bbv)[lane];
  float a0 = 0.f, a1 = 0.f, a2 = 0.f, a3 = 0.f;
  for (int pp = 0; pp < 4; ++pp) {
    const int p = w * 4 + pp;
    const float4 v4 = ((const float4*)(h + ((size_t)sb * cP + p) * cD))[lane];
    float s1 = wave_sum64(v4.x + v4.y + v4.z + v4.w);
    float s2 = wave_sum64(v4.x * v4.x + v4.y * v4.y + v4.z * v4.z + v4.w * v4.w);
    const float m = s1 * (1.f / 256.f);
    const float rst = rsqrtf(s2 * (1.f / 256.f) - m * m + LEPS);
    a0 += (v4.x - m) * rst * g4.x + b4.x;
    a1 += (v4.y - m) * rst * g4.y + b4.y;
    a2 += (v4.z - m) * rst * g4.z + b4.z;
    a3 += (v4.w - m) * rst * g4.w + b4.w;
  }
  __shared__ float sacc[4][256];
  float4* sp = (float4*)sacc[w];
  sp[lane] = make_float4(a0, a1, a2, a3);
  __syncthreads();
  o[(size_t)sb * cD + t] = (sacc[0][t] + sacc[1][t] + sacc[2][t] + sacc[3][t]) * (1.f / 16.f);
}

// ---------------- output SRWM (batch=B) + final projection ----------------
__global__ __launch_bounds__(256, 1) void k_out_srwm(
    const float* __restrict__ gin, float* __restrict__ outp,
    const float* __restrict__ Wy0, const float* __restrict__ Wq0,
    const float* __restrict__ Wk0, const float* __restrict__ wb0,
    const float* __restrict__ lng, const float* __restrict__ lnb,
    const float* __restrict__ outW, const float* __restrict__ outb) {
  const int t = threadIdx.x;
  const int w = t >> 6;
  const int hh = t >> 4, r = t & 15;
  const int b = blockIdx.x;
  float wy[16], wq[16], wk[16], wbr[16];
#pragma unroll
  for (int j = 0; j < 16; ++j) {
    wy[j]  = Wy0[(hh * 16 + r) * 16 + j];
    wq[j]  = Wq0[(hh * 16 + r) * 16 + j];
    wk[j]  = Wk0[(hh * 16 + r) * 16 + j];
    wbr[j] = wb0[(hh * 4 + (r & 3)) * 16 + j];
  }
  float wrow[cNC];
#pragma unroll
  for (int c = 0; c < cNC; ++c) wrow[c] = outW[(size_t)t * cNC + c];
  const float gg = lng[t], bb = lnb[t];
  float xp[16];
#pragma unroll
  for (int s = 0; s < 16; ++s)
    xp[s] = gin[(size_t)(s * cB + b) * cD + t];
  __shared__ float pS[2][4], pQ[2][4];
  __shared__ float pr[2][4][cNC];
  for (int s = 0; s < cS; ++s) {
    const float xv = xp[s];
    float y = 0.f, q = 0.f, k = 0.f, bt = 0.f;
#pragma unroll
    for (int j = 0; j < 16; ++j) {
      const float xj = __shfl(xv, j, 16);
      y += wy[j] * xj; q += wq[j] * xj; k += wk[j] * xj; bt += wbr[j] * xj;
    }
    const float bsig = sigm(bt);
    const float eq = __expf(q), ek = __expf(k);
    float ay = 0.f, vyk = 0.f, vqq = 0.f, vqk = 0.f, vkq = 0.f, vkk = 0.f, vbq = 0.f, vbk = 0.f;
    float ksj[16];
#pragma unroll
    for (int j = 0; j < 16; ++j) {
      const float qj = __shfl(eq, j, 16);
      const float kj = __shfl(ek, j, 16);
      ksj[j] = kj;
      ay  += wy[j]  * qj; vyk += wy[j]  * kj;
      vqq += wq[j]  * qj; vqk += wq[j]  * kj;
      vkq += wk[j]  * qj; vkk += wk[j]  * kj;
      vbq += wbr[j] * qj; vbk += wbr[j] * kj;
    }
    const float rq = frcp(row_sum16(eq));
    const float rk = frcp(row_sum16(ek));
    const float ea = __expf(ay * rq);
    const float vyq = ea * frcp(row_sum16(ea));
    const float b0  = __shfl(bsig, 0, 16);
    const float b1v = __shfl(bsig, 1, 16);
    const float b2v = __shfl(bsig, 2, 16);
    const float b3v = __shfl(bsig, 3, 16);
    const float cy = b0  * (vyq      - vyk * rk) * rk;
    const float cq = b1v * (vqq * rq - vqk * rk) * rk;
    const float ck = b2v * (vkq * rq - vkk * rk) * rk;
    const float cb = b3v * (vbq * rq - vbk * rk) * rk;
#pragma unroll
    for (int j = 0; j < 16; ++j) {
      wy[j] += cy * ksj[j]; wq[j] += cq * ksj[j]; wk[j] += ck * ksj[j]; wbr[j] += cb * ksj[j];
    }
    float s1 = row_sum16(y);
    float s2 = row_sum16(y * y);
    s1 += __shfl_xor(s1, 16, 64); s1 += __shfl_xor(s1, 32, 64);
    s2 += __shfl_xor(s2, 16, 64); s2 += __shfl_xor(s2, 32, 64);
    const int db = s & 1;
    if ((t & 63) == 0) { pS[db][w] = s1; pQ[db][w] = s2; }
    __syncthreads();
    const float sm1 = pS[db][0] + pS[db][1] + pS[db][2] + pS[db][3];
    const float sm2 = pQ[db][0] + pQ[db][1] + pQ[db][2] + pQ[db][3];
    const float m = sm1 * (1.f / 256.f);
    const float var = sm2 * (1.f / 256.f) - m * m;
    const float lnt = (y - m) * rsqrtf(var + LEPS) * gg + bb;
    float pv[cNC];
#pragma unroll
    for (int c = 0; c < cNC; ++c) {
      float p = row_sum16(lnt * wrow[c]);
      p += __shfl_xor(p, 16, 64);
      p += __shfl_xor(p, 32, 64);
      pv[c] = p;
    }
    if ((t & 63) == 0) {
#pragma unroll
      for (int c = 0; c < cNC; ++c) pr[db][w][c] = pv[c];
    }
    __syncthreads();
    if (t < cNC) {
      outp[(size_t)(s * cB + b) * cNC + t] =
          outb[t] + pr[db][0][t] + pr[db][1][t] + pr[db][2][t] + pr[db][3][t];
    }
  }
}

extern "C" void kernel_launch(void* const* d_in, const int* in_sizes, int n_in,
                              void* d_out, int out_size, void* d_ws, size_t ws_size,
                              hipStream_t stream) {
  const float* x     = (const float*)d_in[0];
  const int*   fb    = (const int*)d_in[1];
  const float* inW   = (const float*)d_in[2];
  const float* inb   = (const float*)d_in[3];
  const float* tkWy  = (const float*)d_in[4];
  const float* tkWq  = (const float*)d_in[5];
  const float* tkWk  = (const float*)d_in[6];
  const float* tkwb  = (const float*)d_in[7];
  const float* tklng = (const float*)d_in[8];
  const float* tklnb = (const float*)d_in[9];
  const float* tkmg  = (const float*)d_in[10];
  const float* tkmb  = (const float*)d_in[11];
  const float* tkmW1 = (const float*)d_in[12];
  const float* tkmb1 = (const float*)d_in[13];
  const float* tkmW2 = (const float*)d_in[14];
  const float* tkmb2 = (const float*)d_in[15];
  const float* chWy  = (const float*)d_in[16];
  const float* chWq  = (const float*)d_in[17];
  const float* chWk  = (const float*)d_in[18];
  const float* chwb  = (const float*)d_in[19];
  const float* chlng = (const float*)d_in[20];
  const float* chlnb = (const float*)d_in[21];
  const float* chmg  = (const float*)d_in[22];
  const float* chmb  = (const float*)d_in[23];
  const float* chmW1 = (const float*)d_in[24];
  const float* chmb1 = (const float*)d_in[25];
  const float* chmW2 = (const float*)d_in[26];
  const float* chmb2 = (const float*)d_in[27];
  const float* flng  = (const float*)d_in[28];
  const float* flnb  = (const float*)d_in[29];
  const float* oWy   = (const float*)d_in[30];
  const float* oWq   = (const float*)d_in[31];
  const float* oWk   = (const float*)d_in[32];
  const float* owb   = (const float*)d_in[33];
  const float* olng  = (const float*)d_in[34];
  const float* olnb  = (const float*)d_in[35];
  const float* outW  = (const float*)d_in[36];
  const float* outb  = (const float*)d_in[37];

  float* h    = (float*)d_ws;                               // (S,B,P,D) fp32 = 2 MB
  float* gbuf = h + (size_t)cS * cB * cP * cD;              // (S,B,D)
  float* outp = (float*)d_out;                              // (S,B,NC) fp32

  k_embed<<<dim3(cS * cB * cP), dim3(256), 0, stream>>>(x, fb, inW, inb, h);
  for (int i = 0; i < 2; ++i) {
    k_tok_srwm<<<dim3(128), dim3(256), 0, stream>>>(
        h, tkWy + i * 256, tkWq + i * 256, tkWk + i * 256, tkwb + i * 64,
        tklng + i * 16, tklnb + i * 16);
    k_tok_mixer<<<dim3(cS * cB), dim3(256), 0, stream>>>(
        h, tkmg + i * 256, tkmb + i * 256, tkmW1 + i * 1024, tkmb1 + i * 64,
        tkmW2 + i * 1024, tkmb2 + i * 16);
    k_ch_srwm_mix<<<dim3(cB * cP), dim3(256), 0, stream>>>(
        h, chWy + i * 4096, chWq + i * 4096, chWk + i * 4096, chwb + i * 1024,
        chlng + i * 256, chlnb + i * 256,
        chmg + i * 256, chmb + i * 256, chmW1 + i * 32768, chmb1 + i * 128,
        chmW2 + i * 32768, chmb2 + i * 256);
  }
  k_fln_mean<<<dim3(cS * cB), dim3(256), 0, stream>>>(h, flng, flnb, gbuf);
  k_out_srwm<<<dim3(cB), dim3(256), 0, stream>>>(
      gbuf, outp, oWy, oWq, oWk, owb, olng, olnb, outW, outb);
}